// Round 3
// baseline (1289.252 us; speedup 1.0000x reference)
//
#include <hip/hip_runtime.h>

typedef unsigned short u16;
typedef __attribute__((ext_vector_type(8))) short bf16x8;
typedef __attribute__((ext_vector_type(4))) float f32x4;
typedef __attribute__((ext_vector_type(2))) float f32x2;
typedef __attribute__((ext_vector_type(4))) unsigned u32x4;

#define T_LEN 256
#define HID   512
#define VOCABN 32000
#define SCAN_WGS 16
#define FC_TILES 8000   // 32 bm x 250 bn

__device__ __forceinline__ u16 f2bf(float f) {
  union { float f; unsigned u; } v; v.f = f;
  return (u16)((v.u + 0x7fffu + ((v.u >> 16) & 1u)) >> 16);
}
__device__ __forceinline__ float fast_tanh(float x) {
  return 1.f - 2.f / (__expf(2.f * x) + 1.f);
}

typedef __attribute__((address_space(1))) void as1v;
typedef __attribute__((address_space(3))) void as3v;
__device__ __forceinline__ void gload_lds16(const u16* g, u16* l) {
  __builtin_amdgcn_global_load_lds((as1v*)g, (as3v*)l, 16, 0, 0);
}

// ---------------- K1: embedding gather -> X bf16 [4096][512] ----------------
__global__ __launch_bounds__(256) void k_gather(const int* __restrict__ idx,
                                                const float* __restrict__ emb,
                                                u16* __restrict__ X) {
  int row0 = blockIdx.x * 8;
  for (int i = threadIdx.x; i < 8 * 128; i += 256) {
    int r = i >> 7, cb = i & 127;
    int row = row0 + r;
    int e = idx[row];
    float4 v = *(const float4*)&emb[(long)e * HID + cb * 4];
    ushort4 o; o.x = f2bf(v.x); o.y = f2bf(v.y); o.z = f2bf(v.z); o.w = f2bf(v.w);
    *(ushort4*)&X[(long)row * HID + cb * 4] = o;
  }
}

// ---------------- K2: build Wh/Wx bf16 [2048][512] + bias4 f32 [2048] -------
__global__ __launch_bounds__(256) void k_wconv(const float* __restrict__ Wf, const float* __restrict__ Wi,
                                               const float* __restrict__ Wc, const float* __restrict__ Wo,
                                               const float* __restrict__ bfv, const float* __restrict__ biv,
                                               const float* __restrict__ bcv, const float* __restrict__ bov,
                                               u16* __restrict__ Wh, u16* __restrict__ Wx,
                                               float* __restrict__ bias4) {
  int i = blockIdx.x * 256 + threadIdx.x;      // r=i>>7 in [0,2048), kb=i&127
  int r = i >> 7, kb = i & 127;
  int gate = r >> 9, j = r & 511;
  const float* W = gate == 0 ? Wf : gate == 1 ? Wi : gate == 2 ? Wc : Wo;
  float4 vh = *(const float4*)&W[(long)j * 1024 + kb * 4];
  float4 vx = *(const float4*)&W[(long)j * 1024 + 512 + kb * 4];
  ushort4 oh; oh.x = f2bf(vh.x); oh.y = f2bf(vh.y); oh.z = f2bf(vh.z); oh.w = f2bf(vh.w);
  ushort4 ox; ox.x = f2bf(vx.x); ox.y = f2bf(vx.y); ox.z = f2bf(vx.z); ox.w = f2bf(vx.w);
  *(ushort4*)&Wh[(long)r * 512 + kb * 4] = oh;
  *(ushort4*)&Wx[(long)r * 512 + kb * 4] = ox;
  if (kb == 0) {
    const float* bsrc = gate == 0 ? bfv : gate == 1 ? biv : gate == 2 ? bcv : bov;
    bias4[r] = bsrc[j];
  }
}

// ---------------- K3: fcW f32 -> bf16 [32000][512] --------------------------
__global__ __launch_bounds__(256) void k_fcconv(const float* __restrict__ Wsrc, u16* __restrict__ Wdst) {
  long c = (long)blockIdx.x * 256 + threadIdx.x;   // float4 id, 4,096,000 exact
  float4 v = *(const float4*)&Wsrc[c * 4];
  ushort4 o; o.x = f2bf(v.x); o.y = f2bf(v.y); o.z = f2bf(v.z); o.w = f2bf(v.w);
  *(ushort4*)&Wdst[c * 4] = o;
}

// ---------------- K4: xw GEMM  C[4096][2048] = X @ Wx^T + bias --------------
__global__ __launch_bounds__(256) void k_gemm(const u16* __restrict__ A, const u16* __restrict__ B,
                                              const float* __restrict__ bias, float* __restrict__ C,
                                              int N) {
  __shared__ __align__(16) u16 As[128 * 32];
  __shared__ __align__(16) u16 Bs[128 * 32];
  const int K = 512;
  int tid = threadIdx.x, wave = tid >> 6, lane = tid & 63;
  int nbx = gridDim.x, nby = gridDim.y;
  int id = blockIdx.y * nbx + blockIdx.x;
  int nwg = nbx * nby, q = nwg >> 3;
  int swz = (id & 7) * q + (id >> 3);
  int bm = swz % nby, bn = swz / nby;
  int wr = wave >> 1, wc = wave & 1;
  f32x4 acc[4][4] = {};
  const u16* ga = A + (long)(bm * 128 + (tid >> 2)) * K + (tid & 3) * 8;
  const u16* gb = B + (long)(bn * 128 + (tid >> 2)) * K + (tid & 3) * 8;
  u16* lA = &As[wave * 512];
  u16* lB = &Bs[wave * 512];
  for (int kk = 0; kk < K; kk += 32) {
    gload_lds16(ga + kk, lA);
    gload_lds16(ga + 64 * K + kk, lA + 2048);
    gload_lds16(gb + kk, lB);
    gload_lds16(gb + 64 * K + kk, lB + 2048);
    __syncthreads();
    bf16x8 af[4], bfr[4];
    int arow = wr * 64 + (lane & 15);
    int brow = wc * 64 + (lane & 15);
    int kcol = (lane >> 4) * 8;
#pragma unroll
    for (int m = 0; m < 4; m++) af[m] = *(const bf16x8*)&As[(arow + m * 16) * 32 + kcol];
#pragma unroll
    for (int n = 0; n < 4; n++) bfr[n] = *(const bf16x8*)&Bs[(brow + n * 16) * 32 + kcol];
#pragma unroll
    for (int m = 0; m < 4; m++)
#pragma unroll
      for (int n = 0; n < 4; n++)
        acc[m][n] = __builtin_amdgcn_mfma_f32_16x16x32_bf16(af[m], bfr[n], acc[m][n], 0, 0, 0);
    __syncthreads();
  }
  int c0 = bn * 128 + wc * 64 + (lane & 15);
  int r0 = bm * 128 + wr * 64 + (lane >> 4) * 4;
#pragma unroll
  for (int n = 0; n < 4; n++) {
    float bv = bias[c0 + n * 16];
#pragma unroll
    for (int m = 0; m < 4; m++) {
      f32x4 v = acc[m][n];
#pragma unroll
      for (int rr = 0; rr < 4; rr++)
        C[(long)(r0 + m * 16 + rr) * N + (c0 + n * 16)] = v[rr] + bv;
    }
  }
}

// ---------------- K5: scan ONLY (16 WGs, machine otherwise idle) ------------
// hint-flag + sentinel-validate exchange, identical protocol to R2 but with
// zero FC interference. No frontier publication needed (FC runs after).
__global__ __launch_bounds__(256) void k_scan(
    const u16* __restrict__ Wh, const float* __restrict__ xw,
    u16* __restrict__ hs, unsigned* __restrict__ flags) {
  __shared__ float gates[2 * 16 * 133];
  int tid = threadIdx.x, wave = tid >> 6, lane = tid & 63;
  int g = blockIdx.x;
  int l4 = lane & 15, hi = lane >> 4;
  bf16x8 wreg[2][16];
#pragma unroll
  for (int n = 0; n < 2; n++) {
    int c = wave * 32 + n * 16 + l4;                 // local col [0,128)
    int grow = ((c >> 5) << 9) + (g << 5) + (c & 31);
    const u16* base = Wh + ((long)grow << 9) + (hi << 3);
#pragma unroll
    for (int kt = 0; kt < 16; kt++) wreg[n][kt] = *(const bf16x8*)(base + (kt << 5));
  }

  float cs0 = 0.f, cs1 = 0.f;
  int u0 = (tid & 15) * 2, b = tid >> 4;
  const float* xwt = xw + ((long)b << 8) * 2048 + (g << 5) + u0;

  for (int t = 0; t < T_LEN; t++) {
    f32x2 xv[4];
#pragma unroll
    for (int gt = 0; gt < 4; gt++) xv[gt] = *(const f32x2*)(xwt + (long)t * 2048 + (gt << 9));

    f32x4 acc[2] = {};
    if (t > 0) {
      // 1) cheap gate: one 64B flag line
      const unsigned* fl = flags + ((t - 1) << 4) + (lane & 15);
      for (;;) {
        unsigned v;
        asm volatile("global_load_dword %0, %1, off sc0 sc1\n\ts_waitcnt vmcnt(0)"
                     : "=v"(v) : "v"(fl) : "memory");
        if (__all(v != 0u)) break;
        __builtin_amdgcn_s_sleep(1);
      }
      // 2) one validated h load (sentinel = truth; retries rare)
      const u16* hrow = hs + (((long)(t - 1) * 16 + l4) << 9) + (hi << 3);
      bf16x8 af[16];
      for (;;) {
#pragma unroll
        for (int kt = 0; kt < 16; kt++)
          asm volatile("global_load_dwordx4 %0, %1, off sc0 sc1"
                       : "=v"(af[kt]) : "v"(hrow + (kt << 5)) : "memory");
        asm volatile("s_waitcnt vmcnt(0)" ::: "memory");
        __builtin_amdgcn_sched_barrier(0);
        unsigned mx = 0;
#pragma unroll
        for (int kt = 0; kt < 16; kt++) {
          u32x4 d = __builtin_bit_cast(u32x4, af[kt]);
          unsigned m0 = d.x > d.y ? d.x : d.y;
          unsigned m1 = d.z > d.w ? d.z : d.w;
          unsigned m2 = m0 > m1 ? m0 : m1;
          mx = mx > m2 ? mx : m2;
        }
        if (__all(mx != 0xFFFFFFFFu)) break;
      }
#pragma unroll
      for (int kt = 0; kt < 16; kt++) {
        acc[0] = __builtin_amdgcn_mfma_f32_16x16x32_bf16(af[kt], wreg[0][kt], acc[0], 0, 0, 0);
        acc[1] = __builtin_amdgcn_mfma_f32_16x16x32_bf16(af[kt], wreg[1][kt], acc[1], 0, 0, 0);
      }
    }
    int par = t & 1;
#pragma unroll
    for (int n = 0; n < 2; n++) {
      int c = wave * 32 + n * 16 + l4;
#pragma unroll
      for (int rr = 0; rr < 4; rr++) gates[(par * 16 + hi * 4 + rr) * 133 + c] = acc[n][rr];
    }
    __syncthreads();                                 // the ONE barrier per step
    float p0[4], p1[4];
#pragma unroll
    for (int gt = 0; gt < 4; gt++) {
      p0[gt] = gates[(par * 16 + b) * 133 + (gt << 5) + u0]     + xv[gt].x;
      p1[gt] = gates[(par * 16 + b) * 133 + (gt << 5) + u0 + 1] + xv[gt].y;
    }
    float f0 = 1.f / (1.f + __expf(-p0[0]));
    float i0 = 1.f / (1.f + __expf(-p0[1]));
    cs0 = cs0 * f0 + i0 * fast_tanh(p0[2]);
    float h0 = p0[3] * fast_tanh(cs0);
    float f1 = 1.f / (1.f + __expf(-p1[0]));
    float i1 = 1.f / (1.f + __expf(-p1[1]));
    cs1 = cs1 * f1 + i1 * fast_tanh(p1[2]);
    float h1 = p1[3] * fast_tanh(cs1);

    unsigned hv = (unsigned)f2bf(h0) | ((unsigned)f2bf(h1) << 16);
    unsigned* hp = (unsigned*)(hs + (((long)t * 16 + b) << 9) + (g << 5) + u0);
    asm volatile("global_store_dword %0, %1, off sc0 sc1" :: "v"(hp), "v"(hv) : "memory");
    if (tid == 0) {
      unsigned one = 1u;
      unsigned* fp = flags + (t << 4) + g;
      asm volatile("global_store_dword %0, %1, off sc0 sc1" :: "v"(fp), "v"(one) : "memory");
    }
  }
}

// ---------------- K5b: FC GEMM + partial softmax (no gating) ----------------
__global__ __launch_bounds__(256) void k_fc(
    const u16* __restrict__ hs, const u16* __restrict__ fcWb, const float* __restrict__ fcb,
    float* __restrict__ C, float* __restrict__ part) {
  __shared__ __align__(16) u16 As[128 * 32];
  __shared__ __align__(16) u16 Bs[128 * 32];
  const int K = 512;
  int tid = threadIdx.x, wave = tid >> 6, lane = tid & 63;
  // XCD-aware swizzle: 8000 % 8 == 0 -> bijective chunking; bm-major within
  // an XCD so A-panels (hs rows) stay L2-local.
  int id = blockIdx.x;
  int swz = (id & 7) * (FC_TILES / 8) + (id >> 3);
  int bm = swz / 250, bn = swz % 250;
  int wr = wave >> 1, wc = wave & 1;
  f32x4 acc[4][4] = {};
  const u16* ga = hs + (long)(bm * 128 + (tid >> 2)) * K + (tid & 3) * 8;
  const u16* gb = fcWb + (long)(bn * 128 + (tid >> 2)) * K + (tid & 3) * 8;
  u16* lA = &As[wave * 512];
  u16* lB = &Bs[wave * 512];
  for (int kk = 0; kk < K; kk += 32) {
    gload_lds16(ga + kk, lA);
    gload_lds16(ga + 64 * K + kk, lA + 2048);
    gload_lds16(gb + kk, lB);
    gload_lds16(gb + 64 * K + kk, lB + 2048);
    __syncthreads();
    bf16x8 af[4], bfr[4];
    int arow = wr * 64 + (lane & 15);
    int brow = wc * 64 + (lane & 15);
    int kcol = (lane >> 4) * 8;
#pragma unroll
    for (int m = 0; m < 4; m++) af[m] = *(const bf16x8*)&As[(arow + m * 16) * 32 + kcol];
#pragma unroll
    for (int n = 0; n < 4; n++) bfr[n] = *(const bf16x8*)&Bs[(brow + n * 16) * 32 + kcol];
#pragma unroll
    for (int m = 0; m < 4; m++)
#pragma unroll
      for (int n = 0; n < 4; n++)
        acc[m][n] = __builtin_amdgcn_mfma_f32_16x16x32_bf16(af[m], bfr[n], acc[m][n], 0, 0, 0);
    __syncthreads();
  }
  int c0 = bn * 128 + wc * 64 + (lane & 15);
  float bv[4];
#pragma unroll
  for (int n = 0; n < 4; n++) bv[n] = fcb[c0 + n * 16];
#pragma unroll
  for (int m = 0; m < 4; m++) {
#pragma unroll
    for (int rr = 0; rr < 4; rr++) {
      int p = bm * 128 + wr * 64 + m * 16 + (lane >> 4) * 4 + rr;   // physical hs row
      int row = (p & 15) * 256 + (p >> 4);                          // logical logit row
      float v0 = acc[m][0][rr] + bv[0];
      float v1 = acc[m][1][rr] + bv[1];
      float v2 = acc[m][2][rr] + bv[2];
      float v3 = acc[m][3][rr] + bv[3];
      float* Cr = C + (long)row * VOCABN + c0;
      __builtin_nontemporal_store(v0, &Cr[0]);
      __builtin_nontemporal_store(v1, &Cr[16]);
      __builtin_nontemporal_store(v2, &Cr[32]);
      __builtin_nontemporal_store(v3, &Cr[48]);
      float mx = fmaxf(fmaxf(v0, v1), fmaxf(v2, v3));
      float ss = __expf(v0 - mx) + __expf(v1 - mx) + __expf(v2 - mx) + __expf(v3 - mx);
#pragma unroll
      for (int d = 1; d < 16; d <<= 1) {
        float om = __shfl_xor(mx, d, 64);
        float os = __shfl_xor(ss, d, 64);
        float nm = fmaxf(mx, om);
        ss = ss * __expf(mx - nm) + os * __expf(om - nm);
        mx = nm;
      }
      if ((lane & 15) == 0) {
        f32x2 pr; pr.x = mx; pr.y = ss;
        __builtin_nontemporal_store(pr, (f32x2*)&part[((long)row * 500 + bn * 2 + wc) * 2]);
      }
    }
  }
}

// ---------------- K6: combine partials -> nll per row -----------------------
__global__ __launch_bounds__(256) void k_nllred(const float* __restrict__ part,
                                                const float* __restrict__ logits,
                                                const int* __restrict__ tgt,
                                                float* __restrict__ nll) {
  int row = blockIdx.x * 4 + (threadIdx.x >> 6);
  int lane = threadIdx.x & 63;
  const float* P = part + (long)row * 1000;
  float m = -1e30f, s = 0.f;
  for (int p = lane; p < 500; p += 64) {
    float2 v = *(const float2*)&P[p * 2];
    float nm = fmaxf(m, v.x);
    s = s * __expf(m - nm) + v.y * __expf(v.x - nm);
    m = nm;
  }
#pragma unroll
  for (int d = 1; d < 64; d <<= 1) {
    float om = __shfl_xor(m, d, 64);
    float os = __shfl_xor(s, d, 64);
    float nm = fmaxf(m, om);
    s = s * __expf(m - nm) + os * __expf(om - nm);
    m = nm;
  }
  if (lane == 0)
    nll[row] = (m + __logf(s)) - logits[(long)row * VOCABN + tgt[row]];
}

// ---------------- K7: deterministic mean of nll -> loss ---------------------
__global__ __launch_bounds__(256) void k_loss(const float* __restrict__ nll, float* __restrict__ out) {
  __shared__ float sm[256];
  float acc = 0.f;
  for (int i = threadIdx.x; i < 4096; i += 256) acc += nll[i];
  sm[threadIdx.x] = acc;
  __syncthreads();
  for (int off = 128; off > 0; off >>= 1) {
    if (threadIdx.x < off) sm[threadIdx.x] += sm[threadIdx.x + off];
    __syncthreads();
  }
  if (threadIdx.x == 0) out[0] = sm[0] * (1.f / 4096.f);
}

extern "C" void kernel_launch(void* const* d_in, const int* in_sizes, int n_in,
                              void* d_out, int out_size, void* d_ws, size_t ws_size,
                              hipStream_t stream) {
  const int*   input_s  = (const int*)d_in[0];
  const int*   output_s = (const int*)d_in[1];
  const float* emb = (const float*)d_in[2];
  const float* Wf  = (const float*)d_in[3];
  const float* bfv = (const float*)d_in[4];
  const float* Wi  = (const float*)d_in[5];
  const float* biv = (const float*)d_in[6];
  const float* Wc  = (const float*)d_in[7];
  const float* bcv = (const float*)d_in[8];
  const float* Wo  = (const float*)d_in[9];
  const float* bov = (const float*)d_in[10];
  const float* fcW = (const float*)d_in[11];
  const float* fcb = (const float*)d_in[12];
  float* out = (float*)d_out;

  char* ws = (char*)d_ws;
  u16*      fcWb  = (u16*)(ws + 0);              // 32,768,000
  u16*      Wx    = (u16*)(ws + 32768000);       //  2,097,152
  u16*      Wh    = (u16*)(ws + 34865152);       //  2,097,152
  u16*      X     = (u16*)(ws + 36962304);       //  4,194,304
  float*    bias4 = (float*)(ws + 41156608);     //      8,192
  unsigned* flags = (unsigned*)(ws + 41164800);  //     16,384  [256][16] hint flags
  float*    nll   = (float*)(ws + 41181312);     //     16,384
  u16*      hs    = (u16*)(ws + 41197696);       //  4,194,304  [t][b][u] bf16
  float*    xw    = (float*)(ws + 45392000);     // 33,554,432  [b*256+t][2048]
  float*    part  = (float*)(ws + 78946432);     // 16,384,000  [row][500][2]

  hipMemsetAsync(flags, 0, 16384, stream);
  hipMemsetAsync(hs, 0xFF, 4194304, stream);     // sentinel: bf16 NaN pattern
  k_gather<<<512, 256, 0, stream>>>(input_s, emb, X);
  k_wconv<<<1024, 256, 0, stream>>>(Wf, Wi, Wc, Wo, bfv, biv, bcv, bov, Wh, Wx, bias4);
  k_fcconv<<<16000, 256, 0, stream>>>(fcW, fcWb);
  dim3 g1(16, 32);
  k_gemm<<<g1, 256, 0, stream>>>(X, Wx, bias4, xw, 2048);
  k_scan<<<SCAN_WGS, 256, 0, stream>>>(Wh, xw, hs, flags);
  k_fc<<<FC_TILES, 256, 0, stream>>>(hs, fcWb, fcb, out, part);
  k_nllred<<<1024, 256, 0, stream>>>(part, out, output_s, nll);
  k_loss<<<1, 256, 0, stream>>>(nll, out + 131072000L);
}

// Round 4
// 823.493 us; speedup vs baseline: 1.5656x; 1.5656x over previous
//
#include <hip/hip_runtime.h>

typedef unsigned short u16;
typedef __attribute__((ext_vector_type(8))) short bf16x8;
typedef __attribute__((ext_vector_type(4))) float f32x4;
typedef __attribute__((ext_vector_type(2))) float f32x2;
typedef __attribute__((ext_vector_type(4))) unsigned u32x4;

#define T_LEN 256
#define HID   512
#define VOCABN 32000
#define SCAN_WGS 16
#define FC_WORKERS 480
#define N_TILES 8000   // 32 bm x 250 bn

__device__ __forceinline__ u16 f2bf(float f) {
  union { float f; unsigned u; } v; v.f = f;
  return (u16)((v.u + 0x7fffu + ((v.u >> 16) & 1u)) >> 16);
}
__device__ __forceinline__ float fast_tanh(float x) {
  return 1.f - 2.f / (__expf(2.f * x) + 1.f);
}

typedef __attribute__((address_space(1))) void as1v;
typedef __attribute__((address_space(3))) void as3v;
__device__ __forceinline__ void gload_lds16(const u16* g, u16* l) {
  __builtin_amdgcn_global_load_lds((as1v*)g, (as3v*)l, 16, 0, 0);
}

// ---------------- K1: embedding gather -> X bf16 [4096][512] ----------------
__global__ __launch_bounds__(256) void k_gather(const int* __restrict__ idx,
                                                const float* __restrict__ emb,
                                                u16* __restrict__ X) {
  int row0 = blockIdx.x * 8;
  for (int i = threadIdx.x; i < 8 * 128; i += 256) {
    int r = i >> 7, cb = i & 127;
    int row = row0 + r;
    int e = idx[row];
    float4 v = *(const float4*)&emb[(long)e * HID + cb * 4];
    ushort4 o; o.x = f2bf(v.x); o.y = f2bf(v.y); o.z = f2bf(v.z); o.w = f2bf(v.w);
    *(ushort4*)&X[(long)row * HID + cb * 4] = o;
  }
}

// ---------------- K2: build Wh/Wx bf16 [2048][512] + bias4 f32 [2048] -------
__global__ __launch_bounds__(256) void k_wconv(const float* __restrict__ Wf, const float* __restrict__ Wi,
                                               const float* __restrict__ Wc, const float* __restrict__ Wo,
                                               const float* __restrict__ bfv, const float* __restrict__ biv,
                                               const float* __restrict__ bcv, const float* __restrict__ bov,
                                               u16* __restrict__ Wh, u16* __restrict__ Wx,
                                               float* __restrict__ bias4) {
  int i = blockIdx.x * 256 + threadIdx.x;      // r=i>>7 in [0,2048), kb=i&127
  int r = i >> 7, kb = i & 127;
  int gate = r >> 9, j = r & 511;
  const float* W = gate == 0 ? Wf : gate == 1 ? Wi : gate == 2 ? Wc : Wo;
  float4 vh = *(const float4*)&W[(long)j * 1024 + kb * 4];
  float4 vx = *(const float4*)&W[(long)j * 1024 + 512 + kb * 4];
  ushort4 oh; oh.x = f2bf(vh.x); oh.y = f2bf(vh.y); oh.z = f2bf(vh.z); oh.w = f2bf(vh.w);
  ushort4 ox; ox.x = f2bf(vx.x); ox.y = f2bf(vx.y); ox.z = f2bf(vx.z); ox.w = f2bf(vx.w);
  *(ushort4*)&Wh[(long)r * 512 + kb * 4] = oh;
  *(ushort4*)&Wx[(long)r * 512 + kb * 4] = ox;
  if (kb == 0) {
    const float* bsrc = gate == 0 ? bfv : gate == 1 ? biv : gate == 2 ? bcv : bov;
    bias4[r] = bsrc[j];
  }
}

// ---------------- K3: fcW f32 -> bf16 [32000][512] --------------------------
__global__ __launch_bounds__(256) void k_fcconv(const float* __restrict__ Wsrc, u16* __restrict__ Wdst) {
  long c = (long)blockIdx.x * 256 + threadIdx.x;   // float4 id, 4,096,000 exact
  float4 v = *(const float4*)&Wsrc[c * 4];
  ushort4 o; o.x = f2bf(v.x); o.y = f2bf(v.y); o.z = f2bf(v.z); o.w = f2bf(v.w);
  *(ushort4*)&Wdst[c * 4] = o;
}

// ---------------- K4: xw GEMM  C[4096][2048] = X @ Wx^T + bias --------------
__global__ __launch_bounds__(256) void k_gemm(const u16* __restrict__ A, const u16* __restrict__ B,
                                              const float* __restrict__ bias, float* __restrict__ C,
                                              int N) {
  __shared__ __align__(16) u16 As[128 * 32];
  __shared__ __align__(16) u16 Bs[128 * 32];
  const int K = 512;
  int tid = threadIdx.x, wave = tid >> 6, lane = tid & 63;
  int nbx = gridDim.x, nby = gridDim.y;
  int id = blockIdx.y * nbx + blockIdx.x;
  int nwg = nbx * nby, q = nwg >> 3;
  int swz = (id & 7) * q + (id >> 3);
  int bm = swz % nby, bn = swz / nby;
  int wr = wave >> 1, wc = wave & 1;
  f32x4 acc[4][4] = {};
  const u16* ga = A + (long)(bm * 128 + (tid >> 2)) * K + (tid & 3) * 8;
  const u16* gb = B + (long)(bn * 128 + (tid >> 2)) * K + (tid & 3) * 8;
  u16* lA = &As[wave * 512];
  u16* lB = &Bs[wave * 512];
  for (int kk = 0; kk < K; kk += 32) {
    gload_lds16(ga + kk, lA);
    gload_lds16(ga + 64 * K + kk, lA + 2048);
    gload_lds16(gb + kk, lB);
    gload_lds16(gb + 64 * K + kk, lB + 2048);
    __syncthreads();
    bf16x8 af[4], bfr[4];
    int arow = wr * 64 + (lane & 15);
    int brow = wc * 64 + (lane & 15);
    int kcol = (lane >> 4) * 8;
#pragma unroll
    for (int m = 0; m < 4; m++) af[m] = *(const bf16x8*)&As[(arow + m * 16) * 32 + kcol];
#pragma unroll
    for (int n = 0; n < 4; n++) bfr[n] = *(const bf16x8*)&Bs[(brow + n * 16) * 32 + kcol];
#pragma unroll
    for (int m = 0; m < 4; m++)
#pragma unroll
      for (int n = 0; n < 4; n++)
        acc[m][n] = __builtin_amdgcn_mfma_f32_16x16x32_bf16(af[m], bfr[n], acc[m][n], 0, 0, 0);
    __syncthreads();
  }
  int c0 = bn * 128 + wc * 64 + (lane & 15);
  int r0 = bm * 128 + wr * 64 + (lane >> 4) * 4;
#pragma unroll
  for (int n = 0; n < 4; n++) {
    float bv = bias[c0 + n * 16];
#pragma unroll
    for (int m = 0; m < 4; m++) {
      f32x4 v = acc[m][n];
#pragma unroll
      for (int rr = 0; rr < 4; rr++)
        C[(long)(r0 + m * 16 + rr) * N + (c0 + n * 16)] = v[rr] + bv;
    }
  }
}

// ---------------- K5: fused scan (single-trip wave0 poll) + FC workers ------
// Scan: producers fire-and-forget sc0sc1 dword h stores (no drain, no flag).
// Wave0 of each WG single-trip polls the h_{t-1} DATA with the 0xFFFFFFFF
// sentinel (hs pre-memset 0xFF; finite bf16 pairs never match), with s_sleep
// backoff; on success it stages the fragments to LDS and publishes the
// per-WG validated frontier vf[g]=t (proof: its sc1 probe saw L3 state).
// All 4 waves then read A from LDS in lockstep -> no intra-WG skew, 4x less
// probe traffic, one L3 trip per step instead of two.
__global__ __launch_bounds__(256, 2) void k_fused(
    const u16* __restrict__ Wh, const float* __restrict__ xw,
    u16* __restrict__ hs, unsigned* __restrict__ vf,
    const u16* __restrict__ fcWb, const float* __restrict__ fcb,
    float* __restrict__ C, float* __restrict__ part) {
  __shared__ __align__(16) char smraw[33408];
  int tid = threadIdx.x, wave = tid >> 6, lane = tid & 63;

  if (blockIdx.x < SCAN_WGS) {
    float* gates = (float*)smraw;                      // [2][16][133] = 17024B
    u16*   Ash   = (u16*)(smraw + 17024);              // [16][64][8] u16 = 16KB
    int g = blockIdx.x;
    int l4 = lane & 15, hi = lane >> 4;
    bf16x8 wreg[2][16];
#pragma unroll
    for (int n = 0; n < 2; n++) {
      int c = wave * 32 + n * 16 + l4;                 // local col [0,128)
      int grow = ((c >> 5) << 9) + (g << 5) + (c & 31);
      const u16* base = Wh + ((long)grow << 9) + (hi << 3);
#pragma unroll
      for (int kt = 0; kt < 16; kt++) wreg[n][kt] = *(const bf16x8*)(base + (kt << 5));
    }
    __builtin_amdgcn_s_setprio(1);                     // scan waves win CU arbitration

    float cs0 = 0.f, cs1 = 0.f;
    int u0 = (tid & 15) * 2, b = tid >> 4;
    const float* xwt = xw + ((long)b << 8) * 2048 + (g << 5) + u0;
    unsigned* vfp = vf + g * 32;                       // per-WG frontier, 128B apart

    for (int t = 0; t < T_LEN; t++) {
      f32x2 xv[4];
#pragma unroll
      for (int gt = 0; gt < 4; gt++) xv[gt] = *(const f32x2*)(xwt + (long)t * 2048 + (gt << 9));

      f32x4 acc[2] = {};
      if (t > 0) {
        if (wave == 0) {
          const u16* hrow = hs + (((long)(t - 1) * 16 + l4) << 9) + (hi << 3);
          bf16x8 af[16];
          for (;;) {
#pragma unroll
            for (int kt = 0; kt < 16; kt++)
              asm volatile("global_load_dwordx4 %0, %1, off sc0 sc1"
                           : "=v"(af[kt]) : "v"(hrow + (kt << 5)) : "memory");
            asm volatile("s_waitcnt vmcnt(0)" ::: "memory");
            __builtin_amdgcn_sched_barrier(0);
            unsigned mx = 0;
#pragma unroll
            for (int kt = 0; kt < 16; kt++) {
              u32x4 d = __builtin_bit_cast(u32x4, af[kt]);
              unsigned m0 = d.x > d.y ? d.x : d.y;
              unsigned m1 = d.z > d.w ? d.z : d.w;
              unsigned m2 = m0 > m1 ? m0 : m1;
              mx = mx > m2 ? mx : m2;
            }
            if (__all(mx != 0xFFFFFFFFu)) break;
            __builtin_amdgcn_s_sleep(2);
          }
          // stage validated A to LDS: [kt][lane] 16B, linear, conflict-free
#pragma unroll
          for (int kt = 0; kt < 16; kt++)
            *(bf16x8*)&Ash[(kt << 9) + (lane << 3)] = af[kt];
          // publish validated frontier (h_{t-1} proven at L3), off critical path
          if (lane == 0) {
            unsigned tv = (unsigned)t;
            asm volatile("global_store_dword %0, %1, off sc0 sc1" :: "v"(vfp), "v"(tv) : "memory");
          }
        }
        __syncthreads();
#pragma unroll
        for (int kt = 0; kt < 16; kt++) {
          bf16x8 afr = *(const bf16x8*)&Ash[(kt << 9) + (lane << 3)];
          acc[0] = __builtin_amdgcn_mfma_f32_16x16x32_bf16(afr, wreg[0][kt], acc[0], 0, 0, 0);
          acc[1] = __builtin_amdgcn_mfma_f32_16x16x32_bf16(afr, wreg[1][kt], acc[1], 0, 0, 0);
        }
      }
      int par = t & 1;
#pragma unroll
      for (int n = 0; n < 2; n++) {
        int c = wave * 32 + n * 16 + l4;
#pragma unroll
        for (int rr = 0; rr < 4; rr++) gates[(par * 16 + hi * 4 + rr) * 133 + c] = acc[n][rr];
      }
      __syncthreads();
      float p0[4], p1[4];
#pragma unroll
      for (int gt = 0; gt < 4; gt++) {
        p0[gt] = gates[(par * 16 + b) * 133 + (gt << 5) + u0]     + xv[gt].x;
        p1[gt] = gates[(par * 16 + b) * 133 + (gt << 5) + u0 + 1] + xv[gt].y;
      }
      float f0 = 1.f / (1.f + __expf(-p0[0]));
      float i0 = 1.f / (1.f + __expf(-p0[1]));
      cs0 = cs0 * f0 + i0 * fast_tanh(p0[2]);
      float h0 = p0[3] * fast_tanh(cs0);
      float f1 = 1.f / (1.f + __expf(-p1[0]));
      float i1 = 1.f / (1.f + __expf(-p1[1]));
      cs1 = cs1 * f1 + i1 * fast_tanh(p1[2]);
      float h1 = p1[3] * fast_tanh(cs1);

      unsigned hv = (unsigned)f2bf(h0) | ((unsigned)f2bf(h1) << 16);
      unsigned* hp = (unsigned*)(hs + (((long)t * 16 + b) << 9) + (g << 5) + u0);
      asm volatile("global_store_dword %0, %1, off sc0 sc1" :: "v"(hp), "v"(hv) : "memory");
    }
    // tail: wave0 validates h_255 at L3, publishes vf[g]=256 (enables bm=31)
    if (wave == 0) {
      const u16* hrow = hs + (((long)255 * 16 + l4) << 9) + (hi << 3);
      for (;;) {
        bf16x8 af[16];
#pragma unroll
        for (int kt = 0; kt < 16; kt++)
          asm volatile("global_load_dwordx4 %0, %1, off sc0 sc1"
                       : "=v"(af[kt]) : "v"(hrow + (kt << 5)) : "memory");
        asm volatile("s_waitcnt vmcnt(0)" ::: "memory");
        __builtin_amdgcn_sched_barrier(0);
        unsigned mx = 0;
#pragma unroll
        for (int kt = 0; kt < 16; kt++) {
          u32x4 d = __builtin_bit_cast(u32x4, af[kt]);
          unsigned m0 = d.x > d.y ? d.x : d.y;
          unsigned m1 = d.z > d.w ? d.z : d.w;
          unsigned m2 = m0 > m1 ? m0 : m1;
          mx = mx > m2 ? mx : m2;
        }
        if (__all(mx != 0xFFFFFFFFu)) break;
        __builtin_amdgcn_s_sleep(2);
      }
      if (lane == 0) {
        unsigned fin = 256u;
        asm volatile("global_store_dword %0, %1, off sc0 sc1" :: "v"(vfp), "v"(fin) : "memory");
      }
    }
  } else {
    // ---------------- persistent FC worker ----------------
    u16* As = (u16*)smraw;                   // [128*32]
    u16* Bs = (u16*)(smraw + 8192);
    const int K = 512;
    int wid = blockIdx.x - SCAN_WGS;
    int polled = -1;
    for (int tile = wid; tile < N_TILES; tile += FC_WORKERS) {
      int bm = tile / 250, bn = tile - bm * 250;   // bm-major follows t-frontier
      if (bm > polled) {
        if (wave == 0) {
          const unsigned* fl = vf + (lane & 15) * 32;   // 16 per-WG frontiers
          unsigned need = (unsigned)(bm * 8 + 8);
          for (;;) {
            unsigned v;
            asm volatile("global_load_dword %0, %1, off sc0 sc1\n\ts_waitcnt vmcnt(0)"
                         : "=v"(v) : "v"(fl) : "memory");
            if (__all((lane & 48) ? 1 : (v >= need))) break;
            __builtin_amdgcn_s_sleep(32);
          }
        }
        __syncthreads();
        polled = bm;
      }
      int wr = wave >> 1, wc = wave & 1;
      f32x4 acc[4][4] = {};
      const u16* ga = hs + (long)(bm * 128 + (tid >> 2)) * K + (tid & 3) * 8;
      const u16* gb = fcWb + (long)(bn * 128 + (tid >> 2)) * K + (tid & 3) * 8;
      u16* lB = &Bs[wave * 512];
      for (int kk = 0; kk < K; kk += 32) {
        gload_lds16(gb + kk, lB);
        gload_lds16(gb + 64 * K + kk, lB + 2048);
        bf16x8 a0, a1;
        asm volatile("global_load_dwordx4 %0, %1, off sc0 sc1" : "=v"(a0) : "v"(ga + kk));
        asm volatile("global_load_dwordx4 %0, %1, off sc0 sc1" : "=v"(a1) : "v"(ga + 64 * K + kk));
        asm volatile("s_waitcnt vmcnt(0)" ::: "memory");
        *(bf16x8*)&As[tid * 8] = a0;
        *(bf16x8*)&As[tid * 8 + 2048] = a1;
        __syncthreads();
        bf16x8 af[4], bfr[4];
        int arow = wr * 64 + (lane & 15);
        int brow = wc * 64 + (lane & 15);
        int kcol = (lane >> 4) * 8;
#pragma unroll
        for (int m = 0; m < 4; m++) af[m] = *(const bf16x8*)&As[(arow + m * 16) * 32 + kcol];
#pragma unroll
        for (int n = 0; n < 4; n++) bfr[n] = *(const bf16x8*)&Bs[(brow + n * 16) * 32 + kcol];
#pragma unroll
        for (int m = 0; m < 4; m++)
#pragma unroll
          for (int n = 0; n < 4; n++)
            acc[m][n] = __builtin_amdgcn_mfma_f32_16x16x32_bf16(af[m], bfr[n], acc[m][n], 0, 0, 0);
        __syncthreads();
      }
      int c0 = bn * 128 + wc * 64 + (lane & 15);
      float bv[4];
#pragma unroll
      for (int n = 0; n < 4; n++) bv[n] = fcb[c0 + n * 16];
#pragma unroll
      for (int m = 0; m < 4; m++) {
#pragma unroll
        for (int rr = 0; rr < 4; rr++) {
          int p = bm * 128 + wr * 64 + m * 16 + (lane >> 4) * 4 + rr;   // physical hs row
          int row = (p & 15) * 256 + (p >> 4);                          // logical logit row
          float v0 = acc[m][0][rr] + bv[0];
          float v1 = acc[m][1][rr] + bv[1];
          float v2 = acc[m][2][rr] + bv[2];
          float v3 = acc[m][3][rr] + bv[3];
          float* Cr = C + (long)row * VOCABN + c0;
          __builtin_nontemporal_store(v0, &Cr[0]);
          __builtin_nontemporal_store(v1, &Cr[16]);
          __builtin_nontemporal_store(v2, &Cr[32]);
          __builtin_nontemporal_store(v3, &Cr[48]);
          float mx = fmaxf(fmaxf(v0, v1), fmaxf(v2, v3));
          float ss = __expf(v0 - mx) + __expf(v1 - mx) + __expf(v2 - mx) + __expf(v3 - mx);
#pragma unroll
          for (int d = 1; d < 16; d <<= 1) {
            float om = __shfl_xor(mx, d, 64);
            float os = __shfl_xor(ss, d, 64);
            float nm = fmaxf(mx, om);
            ss = ss * __expf(mx - nm) + os * __expf(om - nm);
            mx = nm;
          }
          if ((lane & 15) == 0) {
            f32x2 pr; pr.x = mx; pr.y = ss;
            __builtin_nontemporal_store(pr, (f32x2*)&part[((long)row * 500 + bn * 2 + wc) * 2]);
          }
        }
      }
    }
  }
}

// ---------------- K6: combine partials -> nll per row -----------------------
__global__ __launch_bounds__(256) void k_nllred(const float* __restrict__ part,
                                                const float* __restrict__ logits,
                                                const int* __restrict__ tgt,
                                                float* __restrict__ nll) {
  int row = blockIdx.x * 4 + (threadIdx.x >> 6);
  int lane = threadIdx.x & 63;
  const float* P = part + (long)row * 1000;
  float m = -1e30f, s = 0.f;
  for (int p = lane; p < 500; p += 64) {
    float2 v = *(const float2*)&P[p * 2];
    float nm = fmaxf(m, v.x);
    s = s * __expf(m - nm) + v.y * __expf(v.x - nm);
    m = nm;
  }
#pragma unroll
  for (int d = 1; d < 64; d <<= 1) {
    float om = __shfl_xor(m, d, 64);
    float os = __shfl_xor(s, d, 64);
    float nm = fmaxf(m, om);
    s = s * __expf(m - nm) + os * __expf(om - nm);
    m = nm;
  }
  if (lane == 0)
    nll[row] = (m + __logf(s)) - logits[(long)row * VOCABN + tgt[row]];
}

// ---------------- K7: deterministic mean of nll -> loss ---------------------
__global__ __launch_bounds__(256) void k_loss(const float* __restrict__ nll, float* __restrict__ out) {
  __shared__ float sm[256];
  float acc = 0.f;
  for (int i = threadIdx.x; i < 4096; i += 256) acc += nll[i];
  sm[threadIdx.x] = acc;
  __syncthreads();
  for (int off = 128; off > 0; off >>= 1) {
    if (threadIdx.x < off) sm[threadIdx.x] += sm[threadIdx.x + off];
    __syncthreads();
  }
  if (threadIdx.x == 0) out[0] = sm[0] * (1.f / 4096.f);
}

extern "C" void kernel_launch(void* const* d_in, const int* in_sizes, int n_in,
                              void* d_out, int out_size, void* d_ws, size_t ws_size,
                              hipStream_t stream) {
  const int*   input_s  = (const int*)d_in[0];
  const int*   output_s = (const int*)d_in[1];
  const float* emb = (const float*)d_in[2];
  const float* Wf  = (const float*)d_in[3];
  const float* bfv = (const float*)d_in[4];
  const float* Wi  = (const float*)d_in[5];
  const float* biv = (const float*)d_in[6];
  const float* Wc  = (const float*)d_in[7];
  const float* bcv = (const float*)d_in[8];
  const float* Wo  = (const float*)d_in[9];
  const float* bov = (const float*)d_in[10];
  const float* fcW = (const float*)d_in[11];
  const float* fcb = (const float*)d_in[12];
  float* out = (float*)d_out;

  char* ws = (char*)d_ws;
  u16*      fcWb  = (u16*)(ws + 0);              // 32,768,000
  u16*      Wx    = (u16*)(ws + 32768000);       //  2,097,152
  u16*      Wh    = (u16*)(ws + 34865152);       //  2,097,152
  u16*      X     = (u16*)(ws + 36962304);       //  4,194,304
  float*    bias4 = (float*)(ws + 41156608);     //      8,192
  unsigned* vf    = (unsigned*)(ws + 41164800);  //      2,048  (16 x 128B)
  float*    nll   = (float*)(ws + 41181312);     //     16,384
  u16*      hs    = (u16*)(ws + 41197696);       //  4,194,304  [t][b][u] bf16
  float*    xw    = (float*)(ws + 45392000);     // 33,554,432  [b*256+t][2048]
  float*    part  = (float*)(ws + 78946432);     // 16,384,000  [row][500][2]

  hipMemsetAsync(vf, 0, 2048, stream);
  hipMemsetAsync(hs, 0xFF, 4194304, stream);     // sentinel: bf16 NaN pattern
  k_gather<<<512, 256, 0, stream>>>(input_s, emb, X);
  k_wconv<<<1024, 256, 0, stream>>>(Wf, Wi, Wc, Wo, bfv, biv, bcv, bov, Wh, Wx, bias4);
  k_fcconv<<<16000, 256, 0, stream>>>(fcW, fcWb);
  dim3 g1(16, 32);
  k_gemm<<<g1, 256, 0, stream>>>(X, Wx, bias4, xw, 2048);
  k_fused<<<SCAN_WGS + FC_WORKERS, 256, 0, stream>>>(Wh, xw, hs, vf, fcWb, fcb, out, part);
  k_nllred<<<1024, 256, 0, stream>>>(part, out, output_s, nll);
  k_loss<<<1, 256, 0, stream>>>(nll, out + 131072000L);
}